// Round 11
// baseline (125.887 us; speedup 1.0000x reference)
//
#include <hip/hip_runtime.h>

// ConvCaps EM-routing, MI355X. 392 independent problems, one 512-thread block each.
// Thread = (o = t&31 out-cap, kc = t>>5 of 16 k-chunks, 18 k each).
//
// Round-11: explicit DUAL-K interleaved E-body. Evidence: stall-bound (VALU 42%,
// DS ~30%, TA ~30% after W-transpose, nothing saturated; pk-fp32 cut 35% of
// instrs with zero time change). Per-body serial chain (votes->sacc->exp->
// redsum32 5 cross-lane steps->rcp) dominates; interleaving two independent
// k-chains halves its contribution. Round 3 tried this at the 64-VGPR budget
// and spilled; round 9/10 proved 120 VGPR no-spill under (512,2).
// Register economy to fit ~128: W pair loaded per trip (no next-trip W
// prefetch, -32 regs), P read just-in-time from LDS (-32 regs vs round 10),
// bm = base - Mb folded to one reg.
//
// W layout transpose kept (round 10: -9%): Wt[k][j][o][4] lane-contiguous,
// one-shot prep kernel into d_ws (fallback to untransposed if ws too small).
// __launch_bounds__(512,2): measured VGPR unlock (2nd arg acts as min
// WORKGROUPS/CU on this toolchain; (512,4) caps at 64 VGPR and spills).
//
// Math: fused E+M, votes recomputed 3x (M0, E0+M1, E1+M2); unnormalized
// moments  mean = S(uv)/(rs+eps), var = S(uv^2)/(rs+eps) - m^2(2-S1);
// u_k = softmax_o(ln_ap)*c_k, c_k = a/(a+eps); r never materialized.
// Iteration-constant softmax shift Mb = max_o(base). Packed fp32 math;
// DPP {xor1,xor2,xor7,xor15} + ds_swizzle xor16 32-lane reduces.

namespace {

constexpr int NKK = 288;
constexpr float EPSF = 1e-8f;
constexpr float LN2PI = 1.8378770664093453f;

typedef float f32x2 __attribute__((ext_vector_type(2)));

__device__ __forceinline__ float fastrcp(float x) { return __builtin_amdgcn_rcpf(x); }
__device__ __forceinline__ f32x2 splat2(float x) { f32x2 r; r.x = x; r.y = x; return r; }
__device__ __forceinline__ f32x2 fma2(f32x2 a, f32x2 b, f32x2 c) {
    return __builtin_elementwise_fma(a, b, c);
}
__device__ __forceinline__ f32x2 lo2(float4 v) { f32x2 r; r.x = v.x; r.y = v.y; return r; }
__device__ __forceinline__ f32x2 hi2(float4 v) { f32x2 r; r.x = v.z; r.y = v.w; return r; }

template <int CTRL>
__device__ __forceinline__ float dppf(float x) {
    return __int_as_float(__builtin_amdgcn_update_dpp(
        __float_as_int(x), __float_as_int(x), CTRL, 0xF, 0xF, false));
}
__device__ __forceinline__ float swz16(float x) {
    return __int_as_float(__builtin_amdgcn_ds_swizzle(__float_as_int(x), 0x401F));
}

__device__ __forceinline__ float redmax32(float v) {
    v = fmaxf(v, dppf<0xB1>(v));
    v = fmaxf(v, dppf<0x4E>(v));
    v = fmaxf(v, dppf<0x141>(v));
    v = fmaxf(v, dppf<0x140>(v));
    v = fmaxf(v, swz16(v));
    return v;
}
// Dual interleaved 32-lane sum reduces: two independent chains in flight.
__device__ __forceinline__ void redsum32x2(float& a, float& b) {
    float ta, tb;
    ta = dppf<0xB1>(a);  tb = dppf<0xB1>(b);  a += ta; b += tb;
    ta = dppf<0x4E>(a);  tb = dppf<0x4E>(b);  a += ta; b += tb;
    ta = dppf<0x141>(a); tb = dppf<0x141>(b); a += ta; b += tb;
    ta = dppf<0x140>(a); tb = dppf<0x140>(b); a += ta; b += tb;
    ta = swz16(a);       tb = swz16(b);       a += ta; b += tb;
}

// W row loader. TR: Wt[k][j][o][4] (lane-contiguous per quarter).
template <bool TR>
__device__ __forceinline__ void load_w(float4* WD, const float* __restrict__ Wg,
                                       const float4* __restrict__ Wt4, int k, int o) {
    if constexpr (TR) {
        const float4* wp = Wt4 + (size_t)(k * 4) * 32 + o;
        WD[0] = wp[0]; WD[1] = wp[32]; WD[2] = wp[64]; WD[3] = wp[96];
    } else {
        const float4* wp = (const float4*)&Wg[(k * 32 + o) * 16];
        WD[0] = wp[0]; WD[1] = wp[1]; WD[2] = wp[2]; WD[3] = wp[3];
    }
}

// Prep: Wg[k][o][p16] -> Wt[k][j4][o][4f].
__global__ __launch_bounds__(256)
void transpose_w(const float* __restrict__ Wg, float* __restrict__ Wt) {
    const int idx = blockIdx.x * 256 + threadIdx.x;   // grid = 144 blocks exactly
    const int j = idx & 3;
    const int o = (idx >> 2) & 31;
    const int k = idx >> 7;
    const float4 v = ((const float4*)Wg)[idx];
    ((float4*)Wt)[((k * 4 + j) * 32 + o)] = v;
}

template <bool TR>
__global__ __launch_bounds__(512, 2)
void caps_em_kernel(const float* __restrict__ x,
                    const float* __restrict__ Wg,
                    const float4* __restrict__ Wt4,
                    const float* __restrict__ bu,
                    const float* __restrict__ ba,
                    float* __restrict__ out)
{
    // LDS: 18432 + 1152 + 33792 + 2176 + 2176 + 256 = 57984 B -> 2 blocks/CU
    __shared__ float p4[NKK * 16];       // pose fragments [k*16+p]
    __shared__ float cIn[NKK];           // a/(a+eps)
    __shared__ float scr[8 * 32 * 33];   // [g][o][ Sv(16) | Sv2(16) | S0 ]
    __shared__ float meanS[32 * 17];     // mean[o*17+p]  (stride 17: conflict-free)
    __shared__ float i2vS[32 * 17];      // 1/(2*std^2)
    __shared__ float actS[32];
    __shared__ float baseS[32];          // log(act) - sum_p log std - 8*ln2pi

    const int n = blockIdx.x;
    const int t = threadIdx.x;

    // ---- gather poses: flat view of tiled (B,kh,kw,oh,ow,512) ----
    for (int idx = t; idx < NKK * 16; idx += 512) {
        unsigned g = (unsigned)n * 4608u + (unsigned)idx;
        unsigned c = g & 511u, rest = g >> 9;
        unsigned ow = rest % 7u; rest /= 7u;
        unsigned oh = rest % 7u; rest /= 7u;
        unsigned kw = rest % 3u; rest /= 3u;
        unsigned kh = rest % 3u;
        unsigned b  = rest / 3u;
        p4[idx] = x[((b*16u + 2u*oh + kh)*16u + 2u*ow + kw)*544u + c];
    }
    // ---- gather acts -> c_k ----
    for (int idx = t; idx < NKK; idx += 512) {
        unsigned g = (unsigned)n * 288u + (unsigned)idx;
        unsigned c = g & 31u, rest = g >> 5;
        unsigned ow = rest % 7u; rest /= 7u;
        unsigned oh = rest % 7u; rest /= 7u;
        unsigned kw = rest % 3u; rest /= 3u;
        unsigned kh = rest % 3u;
        unsigned b  = rest / 3u;
        const float a = x[((b*16u + 2u*oh + kh)*16u + 2u*ow + kw)*544u + 512u + c];
        cIn[idx] = a / (a + EPSF);
    }
    __syncthreads();

    const int o  = t & 31;    // out-cap (== lane&31)
    const int kc = t >> 5;    // k-chunk 0..15 (18 k each)
    const int oo = t >> 4;    // reducer row 0..31
    const int pp = t & 15;    // reducer col 0..15

    float lam = 1.0e-3f;

// Votes for one k with fused sacc (E). Consumes WC (float4[4]) + LDS P row.
#define VOTES_SACC(K_, WC, V2, SACCV)                                      \
    {                                                                      \
        const float4* pp_ = (const float4*)&p4[(K_)*16];                   \
        f32x2 sa0_ = splat2(0.f), sa1_ = splat2(0.f);                      \
        _Pragma("unroll")                                                  \
        for (int i = 0; i < 4; ++i) {                                      \
            const float4 P_ = pp_[i];                                      \
            _Pragma("unroll")                                              \
            for (int h = 0; h < 2; ++h) {                                  \
                const int q = i*2 + h;                                     \
                const f32x2 w0 = (h == 0) ? lo2(WC[0]) : hi2(WC[0]);       \
                const f32x2 w1 = (h == 0) ? lo2(WC[1]) : hi2(WC[1]);       \
                const f32x2 w2 = (h == 0) ? lo2(WC[2]) : hi2(WC[2]);       \
                const f32x2 w3 = (h == 0) ? lo2(WC[3]) : hi2(WC[3]);       \
                f32x2 acc = splat2(P_.x) * w0;                             \
                acc = fma2(splat2(P_.y), w1, acc);                         \
                acc = fma2(splat2(P_.z), w2, acc);                         \
                acc = fma2(splat2(P_.w), w3, acc);                         \
                V2[q] = acc;                                               \
                const f32x2 d = acc - M2[q];                               \
                if (q & 1) sa1_ = fma2(d * d, I2[q], sa1_);                \
                else       sa0_ = fma2(d * d, I2[q], sa0_);                \
            }                                                              \
        }                                                                  \
        const f32x2 sv_ = sa0_ + sa1_;                                     \
        SACCV = sv_.x + sv_.y;                                             \
    }

// Votes for one k, M0 accumulate (uniform r), no cross-k liveness.
#define M0_K(K_, WC)                                                       \
    {                                                                      \
        const float4* pp_ = (const float4*)&p4[(K_)*16];                   \
        const float w_ = cIn[(K_)] * 0.03125f;                             \
        const f32x2 w2_ = splat2(w_);                                      \
        S0 += w_;                                                          \
        _Pragma("unroll")                                                  \
        for (int i = 0; i < 4; ++i) {                                      \
            const float4 P_ = pp_[i];                                      \
            _Pragma("unroll")                                              \
            for (int h = 0; h < 2; ++h) {                                  \
                const int q = i*2 + h;                                     \
                const f32x2 w0 = (h == 0) ? lo2(WC[0]) : hi2(WC[0]);       \
                const f32x2 w1 = (h == 0) ? lo2(WC[1]) : hi2(WC[1]);       \
                const f32x2 w2 = (h == 0) ? lo2(WC[2]) : hi2(WC[2]);       \
                const f32x2 w3 = (h == 0) ? lo2(WC[3]) : hi2(WC[3]);       \
                f32x2 acc = splat2(P_.x) * w0;                             \
                acc = fma2(splat2(P_.y), w1, acc);                         \
                acc = fma2(splat2(P_.z), w2, acc);                         \
                acc = fma2(splat2(P_.w), w3, acc);                         \
                const f32x2 wv = w2_ * acc;                                \
                Svp[q] += wv;                                              \
                Sv2p[q] = fma2(wv, acc, Sv2p[q]);                          \
            }                                                              \
        }                                                                  \
    }

    for (int it = 0; it < 3; ++it) {
        lam += 1.0e-4f;

        float S0 = 0.f;
        f32x2 Svp[8], Sv2p[8];
        #pragma unroll
        for (int q = 0; q < 8; ++q) { Svp[q] = splat2(0.f); Sv2p[q] = splat2(0.f); }

        const int k0b = kc * 18;

        if (it == 0) {
            // ---- M0: uniform r -> u_k = c_k/32 (same for all o) ----
            #pragma unroll 1
            for (int kk = 0; kk < 18; kk += 2) {
                const int k0 = k0b + kk;
                float4 Wa[4], Wb[4];
                load_w<TR>(Wa, Wg, Wt4, k0, o);
                load_w<TR>(Wb, Wg, Wt4, k0 + 1, o);
                M0_K(k0, Wa)
                M0_K(k0 + 1, Wb)
            }
        } else {
            // ---- fused E(prev stats) + M accumulate, dual-k interleave ----
            f32x2 M2[8], I2[8];
            #pragma unroll
            for (int q = 0; q < 8; ++q) {
                f32x2 m; m.x = meanS[o*17 + 2*q]; m.y = meanS[o*17 + 2*q + 1];
                f32x2 iv; iv.x = i2vS[o*17 + 2*q]; iv.y = i2vS[o*17 + 2*q + 1];
                M2[q] = m; I2[q] = iv;
            }
            const float base = baseS[o];
            const float bm = base - redmax32(base);  // base - Mb  (<= 0)
            #pragma unroll 1
            for (int kk = 0; kk < 18; kk += 2) {
                const int k0 = k0b + kk;
                const int k1 = k0 + 1;
                float4 Wa[4], Wb[4];
                load_w<TR>(Wa, Wg, Wt4, k0, o);
                load_w<TR>(Wb, Wg, Wt4, k1, o);
                const float cI0 = cIn[k0];
                const float cI1 = cIn[k1];
                f32x2 v20[8], v21[8];
                float sacc0, sacc1;
                VOTES_SACC(k0, Wa, v20, sacc0)
                VOTES_SACC(k1, Wb, v21, sacc1)
                const float e0 = __expf(bm - sacc0);
                const float e1 = __expf(bm - sacc1);
                float ss0 = e0, ss1 = e1;
                redsum32x2(ss0, ss1);
                const float u0 = e0 * fastrcp(ss0) * cI0;
                const float u1 = e1 * fastrcp(ss1) * cI1;
                S0 += u0 + u1;
                const f32x2 u20 = splat2(u0);
                const f32x2 u21 = splat2(u1);
                #pragma unroll
                for (int q = 0; q < 8; ++q) {
                    const f32x2 uv0 = u20 * v20[q];
                    const f32x2 uv1 = u21 * v21[q];
                    Svp[q] += uv0 + uv1;
                    Sv2p[q] = fma2(uv0, v20[q], fma2(uv1, v21[q], Sv2p[q]));
                }
            }
        }

        // ---- combine kc pairs (partner lane^32, same wave) -> 8 groups ----
        S0 += __shfl_xor(S0, 32, 64);
        #pragma unroll
        for (int q = 0; q < 8; ++q) {
            f32x2 ta, tb;
            ta.x = __shfl_xor(Svp[q].x, 32, 64);
            ta.y = __shfl_xor(Svp[q].y, 32, 64);
            tb.x = __shfl_xor(Sv2p[q].x, 32, 64);
            tb.y = __shfl_xor(Sv2p[q].y, 32, 64);
            Svp[q] += ta;
            Sv2p[q] += tb;
        }
        if ((kc & 1) == 0) {
            float* row = &scr[((kc >> 1)*32 + o)*33];
            #pragma unroll
            for (int q = 0; q < 8; ++q) {
                row[2*q]      = Svp[q].x;  row[2*q + 1]      = Svp[q].y;
                row[16 + 2*q] = Sv2p[q].x; row[16 + 2*q + 1] = Sv2p[q].y;
            }
            row[32] = S0;
        }
        __syncthreads();

        // ---- reduce 8 groups + stats; thread t handles (oo, pp) ----
        {
            float sm = 0.f, s2 = 0.f, rs = 0.f;
            #pragma unroll
            for (int q = 0; q < 8; ++q) {
                const int b0 = (q*32 + oo)*33;
                sm += scr[b0 + pp];
                s2 += scr[b0 + 16 + pp];
                rs += scr[b0 + 32];
            }
            const float inv = 1.0f / (rs + EPSF);
            const float S1  = rs * inv;
            const float m   = sm * inv;
            float var = s2 * inv - m*m*(2.0f - S1);
            var = fmaxf(var, 0.0f) + EPSF;          // std^2 (+eps inside sqrt)
            meanS[oo*17 + pp] = m;
            i2vS [oo*17 + pp] = 0.5f / var;
            scr[oo*33 + pp] = 0.5f * __logf(var);   // log std; q=0 slot owned by this thread
        }
        __syncthreads();
        if (t < 32) {
            float lsum = 0.f;
            #pragma unroll
            for (int p = 0; p < 16; ++p) lsum += scr[t*33 + p];
            float rs = 0.f;
            #pragma unroll
            for (int q = 0; q < 8; ++q) rs += scr[(q*32 + t)*33 + 32];
            const float cost = (16.0f * bu[t] + lsum) * rs;
            const float ao   = 1.0f / (1.0f + __expf(-lam * (ba[t] - cost)));
            actS[t]  = ao;
            baseS[t] = -lsum - 8.0f*LN2PI + __logf(ao);
        }
        __syncthreads();
    }

#undef VOTES_SACC
#undef M0_K

    // ---- output: [mean(512) | act(32)] per n ----
    for (int idx = t; idx < 544; idx += 512) {
        const float v = (idx < 512) ? meanS[(idx >> 4)*17 + (idx & 15)]
                                    : actS[idx - 512];
        out[n*544 + idx] = v;
    }
}

} // namespace

extern "C" void kernel_launch(void* const* d_in, const int* in_sizes, int n_in,
                              void* d_out, int out_size, void* d_ws, size_t ws_size,
                              hipStream_t stream) {
    (void)in_sizes; (void)n_in; (void)out_size;
    const float* x  = (const float*)d_in[0];
    const float* W  = (const float*)d_in[1];
    const float* bu = (const float*)d_in[2];
    const float* ba = (const float*)d_in[3];
    float* out = (float*)d_out;

    const size_t need = (size_t)NKK * 32 * 16 * sizeof(float);
    if (d_ws != nullptr && ws_size >= need) {
        float* Wt = (float*)d_ws;
        transpose_w<<<dim3(144), dim3(256), 0, stream>>>(W, Wt);
        caps_em_kernel<true><<<dim3(392), dim3(512), 0, stream>>>(
            x, W, (const float4*)Wt, bu, ba, out);
    } else {
        caps_em_kernel<false><<<dim3(392), dim3(512), 0, stream>>>(
            x, W, nullptr, bu, ba, out);
    }
}

// Round 12
// 120.927 us; speedup vs baseline: 1.0410x; 1.0410x over previous
//
#include <hip/hip_runtime.h>

// ConvCaps EM-routing, MI355X. 392 independent problems, one 512-thread block each.
// Thread = (o = t&31 out-cap, kc = t>>5 of 16 k-chunks, 18 k each).
//
// Round-12: cross-lane ops moved DS -> VALU via gfx950 permlane{16,32}_swap.
// permlaneN_swap(x,x) returns {x[l], x[l^N]} in lane-dependent order, so
// r0+r1 == xor-N butterfly sum and max(r0,r1) == butterfly max -- no cndmask,
// no LDS round-trip. Removes ~140 DS round-trips per wave (36 E-body redsums,
// redmax, and 33 kc-combine shuffles x3 iters) from the critical path.
// __has_builtin-guarded; fallback = round-10 swizzle/shfl (73us) exactly.
//
// Base structure = round 10 (best, 73us): single-k bodies, P+W 1-deep register
// double-buffer prefetch (dual-k was tried in round 11: forced dropping the
// prefetch to fit 128 VGPR and lost net 6%), W transposed Wt[k][j][o][4]
// (round 10: -9%, cuts TA line traffic 4x), iteration-constant softmax shift
// Mb = max_o(base), pk-fp32 vote/sacc/accum math.
// __launch_bounds__(512,2): measured VGPR unlock (2nd arg acts as min
// WORKGROUPS/CU on this toolchain; (512,4) caps at 64 VGPR and spills).
//
// Math: fused E+M, votes recomputed 3x (M0, E0+M1, E1+M2); unnormalized
// moments  mean = S(uv)/(rs+eps), var = S(uv^2)/(rs+eps) - m^2(2-S1);
// u_k = softmax_o(ln_ap)*c_k, c_k = a/(a+eps); r never materialized.

namespace {

constexpr int NKK = 288;
constexpr float EPSF = 1e-8f;
constexpr float LN2PI = 1.8378770664093453f;

typedef float f32x2 __attribute__((ext_vector_type(2)));

__device__ __forceinline__ float fastrcp(float x) { return __builtin_amdgcn_rcpf(x); }
__device__ __forceinline__ f32x2 splat2(float x) { f32x2 r; r.x = x; r.y = x; return r; }
__device__ __forceinline__ f32x2 fma2(f32x2 a, f32x2 b, f32x2 c) {
    return __builtin_elementwise_fma(a, b, c);
}
__device__ __forceinline__ f32x2 lo2(float4 v) { f32x2 r; r.x = v.x; r.y = v.y; return r; }
__device__ __forceinline__ f32x2 hi2(float4 v) { f32x2 r; r.x = v.z; r.y = v.w; return r; }

// DPP lane permute (VALU pipe). CTRL: 0xB1=quad_perm xor1, 0x4E=quad_perm xor2,
// 0x141=row_half_mirror (xor7), 0x140=row_mirror (xor15).
template <int CTRL>
__device__ __forceinline__ float dppf(float x) {
    return __int_as_float(__builtin_amdgcn_update_dpp(
        __float_as_int(x), __float_as_int(x), CTRL, 0xF, 0xF, false));
}
// ds_swizzle xor16 (fallback path only).
__device__ __forceinline__ float swz16(float x) {
    return __int_as_float(__builtin_amdgcn_ds_swizzle(__float_as_int(x), 0x401F));
}

// xor16 butterfly combine steps, VALU-only via permlane16_swap when available.
__device__ __forceinline__ float xsum16(float x) {
#if __has_builtin(__builtin_amdgcn_permlane16_swap)
    auto r = __builtin_amdgcn_permlane16_swap(__float_as_uint(x), __float_as_uint(x),
                                              false, false);
    return __uint_as_float(r[0]) + __uint_as_float(r[1]);
#else
    return x + swz16(x);
#endif
}
__device__ __forceinline__ float xmax16(float x) {
#if __has_builtin(__builtin_amdgcn_permlane16_swap)
    auto r = __builtin_amdgcn_permlane16_swap(__float_as_uint(x), __float_as_uint(x),
                                              false, false);
    return fmaxf(__uint_as_float(r[0]), __uint_as_float(r[1]));
#else
    return fmaxf(x, swz16(x));
#endif
}
// xor32 butterfly sum (kc-pair combine), VALU-only via permlane32_swap.
__device__ __forceinline__ float xsum32(float x) {
#if __has_builtin(__builtin_amdgcn_permlane32_swap)
    auto r = __builtin_amdgcn_permlane32_swap(__float_as_uint(x), __float_as_uint(x),
                                              false, false);
    return __uint_as_float(r[0]) + __uint_as_float(r[1]);
#else
    return x + __shfl_xor(x, 32, 64);
#endif
}

// Reduce over the 32-lane group (lanes 0-31 / 32-63 independently).
// XOR-mask basis {1,2,7,15,16} spans bits 0..4 -> valid butterfly.
__device__ __forceinline__ float redmax32(float v) {
    v = fmaxf(v, dppf<0xB1>(v));
    v = fmaxf(v, dppf<0x4E>(v));
    v = fmaxf(v, dppf<0x141>(v));
    v = fmaxf(v, dppf<0x140>(v));
    return xmax16(v);
}
__device__ __forceinline__ float redsum32(float v) {
    v += dppf<0xB1>(v);
    v += dppf<0x4E>(v);
    v += dppf<0x141>(v);
    v += dppf<0x140>(v);
    return xsum16(v);
}

// W row loader. TR: Wt[k][j][o][4] (lane-contiguous per quarter).
template <bool TR>
__device__ __forceinline__ void load_w(float4* WD, const float* __restrict__ Wg,
                                       const float4* __restrict__ Wt4, int k, int o) {
    if constexpr (TR) {
        const float4* wp = Wt4 + (size_t)(k * 4) * 32 + o;
        WD[0] = wp[0]; WD[1] = wp[32]; WD[2] = wp[64]; WD[3] = wp[96];
    } else {
        const float4* wp = (const float4*)&Wg[(k * 32 + o) * 16];
        WD[0] = wp[0]; WD[1] = wp[1]; WD[2] = wp[2]; WD[3] = wp[3];
    }
}

// Prep: Wg[k][o][p16] -> Wt[k][j4][o][4f].
__global__ __launch_bounds__(256)
void transpose_w(const float* __restrict__ Wg, float* __restrict__ Wt) {
    const int idx = blockIdx.x * 256 + threadIdx.x;   // grid = 144 blocks exactly
    const int j = idx & 3;
    const int o = (idx >> 2) & 31;
    const int k = idx >> 7;
    const float4 v = ((const float4*)Wg)[idx];
    ((float4*)Wt)[((k * 4 + j) * 32 + o)] = v;
}

template <bool TR>
__global__ __launch_bounds__(512, 2)
void caps_em_kernel(const float* __restrict__ x,
                    const float* __restrict__ Wg,
                    const float4* __restrict__ Wt4,
                    const float* __restrict__ bu,
                    const float* __restrict__ ba,
                    float* __restrict__ out)
{
    // LDS: 18432 + 1152 + 33792 + 2176 + 2176 + 256 = 57984 B -> 2 blocks/CU
    __shared__ float p4[NKK * 16];       // pose fragments [k*16+p]
    __shared__ float cIn[NKK];           // a/(a+eps)
    __shared__ float scr[8 * 32 * 33];   // [g][o][ Sv(16) | Sv2(16) | S0 ]
    __shared__ float meanS[32 * 17];     // mean[o*17+p]  (stride 17: conflict-free)
    __shared__ float i2vS[32 * 17];      // 1/(2*std^2)
    __shared__ float actS[32];
    __shared__ float baseS[32];          // log(act) - sum_p log std - 8*ln2pi

    const int n = blockIdx.x;
    const int t = threadIdx.x;

    // ---- gather poses: flat view of tiled (B,kh,kw,oh,ow,512) ----
    for (int idx = t; idx < NKK * 16; idx += 512) {
        unsigned g = (unsigned)n * 4608u + (unsigned)idx;
        unsigned c = g & 511u, rest = g >> 9;
        unsigned ow = rest % 7u; rest /= 7u;
        unsigned oh = rest % 7u; rest /= 7u;
        unsigned kw = rest % 3u; rest /= 3u;
        unsigned kh = rest % 3u;
        unsigned b  = rest / 3u;
        p4[idx] = x[((b*16u + 2u*oh + kh)*16u + 2u*ow + kw)*544u + c];
    }
    // ---- gather acts -> c_k ----
    for (int idx = t; idx < NKK; idx += 512) {
        unsigned g = (unsigned)n * 288u + (unsigned)idx;
        unsigned c = g & 31u, rest = g >> 5;
        unsigned ow = rest % 7u; rest /= 7u;
        unsigned oh = rest % 7u; rest /= 7u;
        unsigned kw = rest % 3u; rest /= 3u;
        unsigned kh = rest % 3u;
        unsigned b  = rest / 3u;
        const float a = x[((b*16u + 2u*oh + kh)*16u + 2u*ow + kw)*544u + 512u + c];
        cIn[idx] = a / (a + EPSF);
    }
    __syncthreads();

    const int o  = t & 31;    // out-cap (== lane&31)
    const int kc = t >> 5;    // k-chunk 0..15 (18 k each)
    const int oo = t >> 4;    // reducer row 0..31
    const int pp = t & 15;    // reducer col 0..15

    float lam = 1.0e-3f;

// Prefetch P row (LDS broadcast) for K_ into raw float4 regs.
#define LOAD_P(PD, K_)                                                     \
    {                                                                      \
        const float4* pp_ = (const float4*)&p4[(K_)*16];                   \
        PD[0] = pp_[0]; PD[1] = pp_[1]; PD[2] = pp_[2]; PD[3] = pp_[3];    \
    }

// Votes from PC x WC (unpack at use). V2[q], q = i*2+h.
#define VOTES(PC, WC, V2)                                                  \
    _Pragma("unroll")                                                      \
    for (int i = 0; i < 4; ++i) {                                          \
        _Pragma("unroll")                                                  \
        for (int h = 0; h < 2; ++h) {                                      \
            const f32x2 w0 = (h == 0) ? lo2(WC[0]) : hi2(WC[0]);           \
            const f32x2 w1 = (h == 0) ? lo2(WC[1]) : hi2(WC[1]);           \
            const f32x2 w2 = (h == 0) ? lo2(WC[2]) : hi2(WC[2]);           \
            const f32x2 w3 = (h == 0) ? lo2(WC[3]) : hi2(WC[3]);           \
            f32x2 acc = splat2(PC[i].x) * w0;                              \
            acc = fma2(splat2(PC[i].y), w1, acc);                          \
            acc = fma2(splat2(PC[i].z), w2, acc);                          \
            acc = fma2(splat2(PC[i].w), w3, acc);                          \
            V2[i*2 + h] = acc;                                             \
        }                                                                  \
    }

// M0 body: uniform r. Consumes PC/WC, prefetches KN_ into PN/WN.
#define M0_BODY(K_, PC, WC, KN_, PN, WN)                                   \
    {                                                                      \
        const float cI_ = cIn[(K_)];                                       \
        f32x2 v2[8];                                                       \
        VOTES(PC, WC, v2)                                                  \
        LOAD_P(PN, (KN_))                                                  \
        load_w<TR>(WN, Wg, Wt4, (KN_), o);                                 \
        const float w_ = cI_ * 0.03125f;                                   \
        const f32x2 w2_ = splat2(w_);                                      \
        S0 += w_;                                                          \
        _Pragma("unroll")                                                  \
        for (int q = 0; q < 8; ++q) {                                      \
            const f32x2 wv = w2_ * v2[q];                                  \
            Svp[q] += wv;                                                  \
            Sv2p[q] = fma2(wv, v2[q], Sv2p[q]);                            \
        }                                                                  \
    }

// E body: fused E(prev stats)+M accumulate. Consumes PC/WC, prefetches KN_.
#define E_BODY(K_, PC, WC, KN_, PN, WN)                                    \
    {                                                                      \
        const float cI_ = cIn[(K_)];                                       \
        f32x2 v2[8];                                                       \
        VOTES(PC, WC, v2)                                                  \
        LOAD_P(PN, (KN_))                                                  \
        load_w<TR>(WN, Wg, Wt4, (KN_), o);                                 \
        f32x2 sa0 = splat2(0.f), sa1 = splat2(0.f);                        \
        _Pragma("unroll")                                                  \
        for (int q = 0; q < 8; ++q) {                                      \
            const f32x2 d = v2[q] - M2[q];                                 \
            if (q & 1) sa1 = fma2(d * d, I2[q], sa1);                      \
            else       sa0 = fma2(d * d, I2[q], sa0);                      \
        }                                                                  \
        const f32x2 sv = sa0 + sa1;                                        \
        const float lnp = bm - (sv.x + sv.y);                              \
        const float e  = __expf(lnp);                                      \
        const float ss = redsum32(e);                                      \
        const float u = e * fastrcp(ss) * cI_;                             \
        S0 += u;                                                           \
        const f32x2 u2 = splat2(u);                                        \
        _Pragma("unroll")                                                  \
        for (int q = 0; q < 8; ++q) {                                      \
            const f32x2 uv = u2 * v2[q];                                   \
            Svp[q] += uv;                                                  \
            Sv2p[q] = fma2(uv, v2[q], Sv2p[q]);                            \
        }                                                                  \
    }

    for (int it = 0; it < 3; ++it) {
        lam += 1.0e-4f;

        float S0 = 0.f;
        f32x2 Svp[8], Sv2p[8];
        #pragma unroll
        for (int q = 0; q < 8; ++q) { Svp[q] = splat2(0.f); Sv2p[q] = splat2(0.f); }

        const int k0 = kc * 18;
        float4 Pa[4], Pb[4], Wa[4], Wb[4];
        LOAD_P(Pa, k0)
        load_w<TR>(Wa, Wg, Wt4, k0, o);

        if (it == 0) {
            // ---- M0: uniform r -> u_k = c_k/32 (same for all o) ----
            #pragma unroll 1
            for (int kk = 0; kk < 18; kk += 2) {
                const int k = k0 + kk;
                M0_BODY(k, Pa, Wa, k + 1, Pb, Wb)
                const int kn2 = (kk == 16) ? k0 : k + 2;
                M0_BODY(k + 1, Pb, Wb, kn2, Pa, Wa)
            }
        } else {
            // ---- fused E(prev stats) + M accumulate, dual P+W pipeline ----
            f32x2 M2[8], I2[8];
            #pragma unroll
            for (int q = 0; q < 8; ++q) {
                f32x2 m; m.x = meanS[o*17 + 2*q]; m.y = meanS[o*17 + 2*q + 1];
                f32x2 iv; iv.x = i2vS[o*17 + 2*q]; iv.y = i2vS[o*17 + 2*q + 1];
                M2[q] = m; I2[q] = iv;
            }
            const float base = baseS[o];
            const float bm = base - redmax32(base);  // base - Mb (<= 0)
            #pragma unroll 1
            for (int kk = 0; kk < 18; kk += 2) {
                const int k = k0 + kk;
                E_BODY(k, Pa, Wa, k + 1, Pb, Wb)
                const int kn2 = (kk == 16) ? k0 : k + 2;
                E_BODY(k + 1, Pb, Wb, kn2, Pa, Wa)
            }
        }

        // ---- combine kc pairs (partner lane^32, same wave) -> 8 groups ----
        // VALU-only via permlane32_swap (r0+r1 == x + x[lane^32]).
        S0 = xsum32(S0);
        #pragma unroll
        for (int q = 0; q < 8; ++q) {
            Svp[q].x  = xsum32(Svp[q].x);   Svp[q].y  = xsum32(Svp[q].y);
            Sv2p[q].x = xsum32(Sv2p[q].x);  Sv2p[q].y = xsum32(Sv2p[q].y);
        }
        if ((kc & 1) == 0) {
            float* row = &scr[((kc >> 1)*32 + o)*33];
            #pragma unroll
            for (int q = 0; q < 8; ++q) {
                row[2*q]      = Svp[q].x;  row[2*q + 1]      = Svp[q].y;
                row[16 + 2*q] = Sv2p[q].x; row[16 + 2*q + 1] = Sv2p[q].y;
            }
            row[32] = S0;
        }
        __syncthreads();

        // ---- reduce 8 groups + stats; thread t handles (oo, pp) ----
        {
            float sm = 0.f, s2 = 0.f, rs = 0.f;
            #pragma unroll
            for (int q = 0; q < 8; ++q) {
                const int b0 = (q*32 + oo)*33;
                sm += scr[b0 + pp];
                s2 += scr[b0 + 16 + pp];
                rs += scr[b0 + 32];
            }
            const float inv = 1.0f / (rs + EPSF);
            const float S1  = rs * inv;
            const float m   = sm * inv;
            float var = s2 * inv - m*m*(2.0f - S1);
            var = fmaxf(var, 0.0f) + EPSF;          // std^2 (+eps inside sqrt)
            meanS[oo*17 + pp] = m;
            i2vS [oo*17 + pp] = 0.5f / var;
            scr[oo*33 + pp] = 0.5f * __logf(var);   // log std; q=0 slot owned by this thread
        }
        __syncthreads();
        if (t < 32) {
            float lsum = 0.f;
            #pragma unroll
            for (int p = 0; p < 16; ++p) lsum += scr[t*33 + p];
            float rs = 0.f;
            #pragma unroll
            for (int q = 0; q < 8; ++q) rs += scr[(q*32 + t)*33 + 32];
            const float cost = (16.0f * bu[t] + lsum) * rs;
            const float ao   = 1.0f / (1.0f + __expf(-lam * (ba[t] - cost)));
            actS[t]  = ao;
            baseS[t] = -lsum - 8.0f*LN2PI + __logf(ao);
        }
        __syncthreads();
    }

#undef LOAD_P
#undef VOTES
#undef M0_BODY
#undef E_BODY

    // ---- output: [mean(512) | act(32)] per n ----
    for (int idx = t; idx < 544; idx += 512) {
        const float v = (idx < 512) ? meanS[(idx >> 4)*17 + (idx & 15)]
                                    : actS[idx - 512];
        out[n*544 + idx] = v;
    }
}

} // namespace

extern "C" void kernel_launch(void* const* d_in, const int* in_sizes, int n_in,
                              void* d_out, int out_size, void* d_ws, size_t ws_size,
                              hipStream_t stream) {
    (void)in_sizes; (void)n_in; (void)out_size;
    const float* x  = (const float*)d_in[0];
    const float* W  = (const float*)d_in[1];
    const float* bu = (const float*)d_in[2];
    const float* ba = (const float*)d_in[3];
    float* out = (float*)d_out;

    const size_t need = (size_t)NKK * 32 * 16 * sizeof(float);
    if (d_ws != nullptr && ws_size >= need) {
        float* Wt = (float*)d_ws;
        transpose_w<<<dim3(144), dim3(256), 0, stream>>>(W, Wt);
        caps_em_kernel<true><<<dim3(392), dim3(512), 0, stream>>>(
            x, W, (const float4*)Wt, bu, ba, out);
    } else {
        caps_em_kernel<false><<<dim3(392), dim3(512), 0, stream>>>(
            x, W, nullptr, bu, ba, out);
    }
}

// Round 13
// 120.487 us; speedup vs baseline: 1.0448x; 1.0037x over previous
//
#include <hip/hip_runtime.h>

// ConvCaps EM-routing, MI355X. 392 independent problems, one 512-thread block each.
// Thread = (o = t&31 out-cap, kc = t>>5 of 16 k-chunks, 18 k each).
//
// Round-13 changes (register-neutral, on top of round-12's 72us):
//  (a) Fused epilogue: the per-iteration t<32 serial act phase is replaced by
//      a 16-lane DPP butterfly (basis {1,2,7,15} spans bits 0-3; each oo group
//      is one DPP row) summing log-std over p inside the stats phase. Removes
//      1 barrier + ~50-instr serial section (15 waves idled there) x3 iters.
//  (b) log2-domain E: I2 and bm pre-scaled by log2(e) at iteration load, so
//      the per-body exp is a raw v_exp_f32 (2^x) without the dependent
//      x*1.4427 multiply on the critical path.
// Carried: W transpose Wt[k][j][o][4] (round 10, -9%: cuts TA line traffic 4x),
// P+W 1-deep register double-buffer prefetch, permlane16/32_swap butterflies
// (DS->VALU), pk-fp32 math, iteration-constant softmax shift.
// __launch_bounds__(512,2): measured VGPR unlock (2nd arg acts as min
// WORKGROUPS/CU on this toolchain; (512,4) caps at 64 VGPR and spills).
// Dual-k interleave REJECTED (round 11: forced dropping prefetch, net -6%).
//
// Math: fused E+M, votes recomputed 3x (M0, E0+M1, E1+M2); unnormalized
// moments  mean = S(uv)/(rs+eps), var = S(uv^2)/(rs+eps) - m^2(2-S1);
// u_k = softmax_o(ln_ap)*c_k, c_k = a/(a+eps); r never materialized.

namespace {

constexpr int NKK = 288;
constexpr float EPSF = 1e-8f;
constexpr float LN2PI = 1.8378770664093453f;
constexpr float LOG2E = 1.4426950408889634f;

typedef float f32x2 __attribute__((ext_vector_type(2)));

__device__ __forceinline__ float fastrcp(float x) { return __builtin_amdgcn_rcpf(x); }
__device__ __forceinline__ f32x2 splat2(float x) { f32x2 r; r.x = x; r.y = x; return r; }
__device__ __forceinline__ f32x2 fma2(f32x2 a, f32x2 b, f32x2 c) {
    return __builtin_elementwise_fma(a, b, c);
}
__device__ __forceinline__ f32x2 lo2(float4 v) { f32x2 r; r.x = v.x; r.y = v.y; return r; }
__device__ __forceinline__ f32x2 hi2(float4 v) { f32x2 r; r.x = v.z; r.y = v.w; return r; }

// Raw 2^x (v_exp_f32). Fallback keeps exact semantics.
__device__ __forceinline__ float exp2_fast(float x) {
#if __has_builtin(__builtin_amdgcn_exp2f)
    return __builtin_amdgcn_exp2f(x);
#else
    return __expf(x * 0.6931471805599453f);
#endif
}

// DPP lane permute (VALU pipe). CTRL: 0xB1=quad_perm xor1, 0x4E=quad_perm xor2,
// 0x141=row_half_mirror (xor7), 0x140=row_mirror (xor15).
template <int CTRL>
__device__ __forceinline__ float dppf(float x) {
    return __int_as_float(__builtin_amdgcn_update_dpp(
        __float_as_int(x), __float_as_int(x), CTRL, 0xF, 0xF, false));
}
// ds_swizzle xor16 (fallback path only).
__device__ __forceinline__ float swz16(float x) {
    return __int_as_float(__builtin_amdgcn_ds_swizzle(__float_as_int(x), 0x401F));
}

// xor16 butterfly combine steps, VALU-only via permlane16_swap when available.
__device__ __forceinline__ float xsum16(float x) {
#if __has_builtin(__builtin_amdgcn_permlane16_swap)
    auto r = __builtin_amdgcn_permlane16_swap(__float_as_uint(x), __float_as_uint(x),
                                              false, false);
    return __uint_as_float(r[0]) + __uint_as_float(r[1]);
#else
    return x + swz16(x);
#endif
}
__device__ __forceinline__ float xmax16(float x) {
#if __has_builtin(__builtin_amdgcn_permlane16_swap)
    auto r = __builtin_amdgcn_permlane16_swap(__float_as_uint(x), __float_as_uint(x),
                                              false, false);
    return fmaxf(__uint_as_float(r[0]), __uint_as_float(r[1]));
#else
    return fmaxf(x, swz16(x));
#endif
}
// xor32 butterfly sum (kc-pair combine), VALU-only via permlane32_swap.
__device__ __forceinline__ float xsum32(float x) {
#if __has_builtin(__builtin_amdgcn_permlane32_swap)
    auto r = __builtin_amdgcn_permlane32_swap(__float_as_uint(x), __float_as_uint(x),
                                              false, false);
    return __uint_as_float(r[0]) + __uint_as_float(r[1]);
#else
    return x + __shfl_xor(x, 32, 64);
#endif
}

// Reduce over the 32-lane group (lanes 0-31 / 32-63 independently).
// XOR-mask basis {1,2,7,15,16} spans bits 0..4 -> valid butterfly.
__device__ __forceinline__ float redmax32(float v) {
    v = fmaxf(v, dppf<0xB1>(v));
    v = fmaxf(v, dppf<0x4E>(v));
    v = fmaxf(v, dppf<0x141>(v));
    v = fmaxf(v, dppf<0x140>(v));
    return xmax16(v);
}
__device__ __forceinline__ float redsum32(float v) {
    v += dppf<0xB1>(v);
    v += dppf<0x4E>(v);
    v += dppf<0x141>(v);
    v += dppf<0x140>(v);
    return xsum16(v);
}
// Reduce over each 16-lane DPP row (basis {1,2,7,15} spans bits 0..3).
__device__ __forceinline__ float redsum16(float v) {
    v += dppf<0xB1>(v);
    v += dppf<0x4E>(v);
    v += dppf<0x141>(v);
    v += dppf<0x140>(v);
    return v;
}

// W row loader. TR: Wt[k][j][o][4] (lane-contiguous per quarter).
template <bool TR>
__device__ __forceinline__ void load_w(float4* WD, const float* __restrict__ Wg,
                                       const float4* __restrict__ Wt4, int k, int o) {
    if constexpr (TR) {
        const float4* wp = Wt4 + (size_t)(k * 4) * 32 + o;
        WD[0] = wp[0]; WD[1] = wp[32]; WD[2] = wp[64]; WD[3] = wp[96];
    } else {
        const float4* wp = (const float4*)&Wg[(k * 32 + o) * 16];
        WD[0] = wp[0]; WD[1] = wp[1]; WD[2] = wp[2]; WD[3] = wp[3];
    }
}

// Prep: Wg[k][o][p16] -> Wt[k][j4][o][4f].
__global__ __launch_bounds__(256)
void transpose_w(const float* __restrict__ Wg, float* __restrict__ Wt) {
    const int idx = blockIdx.x * 256 + threadIdx.x;   // grid = 144 blocks exactly
    const int j = idx & 3;
    const int o = (idx >> 2) & 31;
    const int k = idx >> 7;
    const float4 v = ((const float4*)Wg)[idx];
    ((float4*)Wt)[((k * 4 + j) * 32 + o)] = v;
}

template <bool TR>
__global__ __launch_bounds__(512, 2)
void caps_em_kernel(const float* __restrict__ x,
                    const float* __restrict__ Wg,
                    const float4* __restrict__ Wt4,
                    const float* __restrict__ bu,
                    const float* __restrict__ ba,
                    float* __restrict__ out)
{
    // LDS: 18432 + 1152 + 33792 + 2176 + 2176 + 256 = 57984 B -> 2 blocks/CU
    __shared__ float p4[NKK * 16];       // pose fragments [k*16+p]
    __shared__ float cIn[NKK];           // a/(a+eps)
    __shared__ float scr[8 * 32 * 33];   // [g][o][ Sv(16) | Sv2(16) | S0 ]
    __shared__ float meanS[32 * 17];     // mean[o*17+p]  (stride 17: conflict-free)
    __shared__ float i2vS[32 * 17];      // 1/(2*std^2)
    __shared__ float actS[32];
    __shared__ float baseS[32];          // log(act) - sum_p log std - 8*ln2pi

    const int n = blockIdx.x;
    const int t = threadIdx.x;

    // ---- gather poses: flat view of tiled (B,kh,kw,oh,ow,512) ----
    for (int idx = t; idx < NKK * 16; idx += 512) {
        unsigned g = (unsigned)n * 4608u + (unsigned)idx;
        unsigned c = g & 511u, rest = g >> 9;
        unsigned ow = rest % 7u; rest /= 7u;
        unsigned oh = rest % 7u; rest /= 7u;
        unsigned kw = rest % 3u; rest /= 3u;
        unsigned kh = rest % 3u;
        unsigned b  = rest / 3u;
        p4[idx] = x[((b*16u + 2u*oh + kh)*16u + 2u*ow + kw)*544u + c];
    }
    // ---- gather acts -> c_k ----
    for (int idx = t; idx < NKK; idx += 512) {
        unsigned g = (unsigned)n * 288u + (unsigned)idx;
        unsigned c = g & 31u, rest = g >> 5;
        unsigned ow = rest % 7u; rest /= 7u;
        unsigned oh = rest % 7u; rest /= 7u;
        unsigned kw = rest % 3u; rest /= 3u;
        unsigned kh = rest % 3u;
        unsigned b  = rest / 3u;
        const float a = x[((b*16u + 2u*oh + kh)*16u + 2u*ow + kw)*544u + 512u + c];
        cIn[idx] = a / (a + EPSF);
    }
    __syncthreads();

    const int o  = t & 31;    // out-cap (== lane&31)
    const int kc = t >> 5;    // k-chunk 0..15 (18 k each)
    const int oo = t >> 4;    // reducer row 0..31
    const int pp = t & 15;    // reducer col 0..15

    float lam = 1.0e-3f;

// Prefetch P row (LDS broadcast) for K_ into raw float4 regs.
#define LOAD_P(PD, K_)                                                     \
    {                                                                      \
        const float4* pp_ = (const float4*)&p4[(K_)*16];                   \
        PD[0] = pp_[0]; PD[1] = pp_[1]; PD[2] = pp_[2]; PD[3] = pp_[3];    \
    }

// Votes from PC x WC (unpack at use). V2[q], q = i*2+h.
#define VOTES(PC, WC, V2)                                                  \
    _Pragma("unroll")                                                      \
    for (int i = 0; i < 4; ++i) {                                          \
        _Pragma("unroll")                                                  \
        for (int h = 0; h < 2; ++h) {                                      \
            const f32x2 w0 = (h == 0) ? lo2(WC[0]) : hi2(WC[0]);           \
            const f32x2 w1 = (h == 0) ? lo2(WC[1]) : hi2(WC[1]);           \
            const f32x2 w2 = (h == 0) ? lo2(WC[2]) : hi2(WC[2]);           \
            const f32x2 w3 = (h == 0) ? lo2(WC[3]) : hi2(WC[3]);           \
            f32x2 acc = splat2(PC[i].x) * w0;                              \
            acc = fma2(splat2(PC[i].y), w1, acc);                          \
            acc = fma2(splat2(PC[i].z), w2, acc);                          \
            acc = fma2(splat2(PC[i].w), w3, acc);                          \
            V2[i*2 + h] = acc;                                             \
        }                                                                  \
    }

// M0 body: uniform r. Consumes PC/WC, prefetches KN_ into PN/WN.
#define M0_BODY(K_, PC, WC, KN_, PN, WN)                                   \
    {                                                                      \
        const float cI_ = cIn[(K_)];                                       \
        f32x2 v2[8];                                                       \
        VOTES(PC, WC, v2)                                                  \
        LOAD_P(PN, (KN_))                                                  \
        load_w<TR>(WN, Wg, Wt4, (KN_), o);                                 \
        const float w_ = cI_ * 0.03125f;                                   \
        const f32x2 w2_ = splat2(w_);                                      \
        S0 += w_;                                                          \
        _Pragma("unroll")                                                  \
        for (int q = 0; q < 8; ++q) {                                      \
            const f32x2 wv = w2_ * v2[q];                                  \
            Svp[q] += wv;                                                  \
            Sv2p[q] = fma2(wv, v2[q], Sv2p[q]);                            \
        }                                                                  \
    }

// E body: fused E(prev stats)+M accumulate, log2 domain. Consumes PC/WC.
#define E_BODY(K_, PC, WC, KN_, PN, WN)                                    \
    {                                                                      \
        const float cI_ = cIn[(K_)];                                       \
        f32x2 v2[8];                                                       \
        VOTES(PC, WC, v2)                                                  \
        LOAD_P(PN, (KN_))                                                  \
        load_w<TR>(WN, Wg, Wt4, (KN_), o);                                 \
        f32x2 sa0 = splat2(0.f), sa1 = splat2(0.f);                        \
        _Pragma("unroll")                                                  \
        for (int q = 0; q < 8; ++q) {                                      \
            const f32x2 d = v2[q] - M2[q];                                 \
            if (q & 1) sa1 = fma2(d * d, I2[q], sa1);                      \
            else       sa0 = fma2(d * d, I2[q], sa0);                      \
        }                                                                  \
        const f32x2 sv = sa0 + sa1;                                        \
        const float e  = exp2_fast(bm - (sv.x + sv.y));                    \
        const float ss = redsum32(e);                                      \
        const float u = e * fastrcp(ss) * cI_;                             \
        S0 += u;                                                           \
        const f32x2 u2 = splat2(u);                                        \
        _Pragma("unroll")                                                  \
        for (int q = 0; q < 8; ++q) {                                      \
            const f32x2 uv = u2 * v2[q];                                   \
            Svp[q] += uv;                                                  \
            Sv2p[q] = fma2(uv, v2[q], Sv2p[q]);                            \
        }                                                                  \
    }

    for (int it = 0; it < 3; ++it) {
        lam += 1.0e-4f;

        float S0 = 0.f;
        f32x2 Svp[8], Sv2p[8];
        #pragma unroll
        for (int q = 0; q < 8; ++q) { Svp[q] = splat2(0.f); Sv2p[q] = splat2(0.f); }

        const int k0 = kc * 18;
        float4 Pa[4], Pb[4], Wa[4], Wb[4];
        LOAD_P(Pa, k0)
        load_w<TR>(Wa, Wg, Wt4, k0, o);

        if (it == 0) {
            // ---- M0: uniform r -> u_k = c_k/32 (same for all o) ----
            #pragma unroll 1
            for (int kk = 0; kk < 18; kk += 2) {
                const int k = k0 + kk;
                M0_BODY(k, Pa, Wa, k + 1, Pb, Wb)
                const int kn2 = (kk == 16) ? k0 : k + 2;
                M0_BODY(k + 1, Pb, Wb, kn2, Pa, Wa)
            }
        } else {
            // ---- fused E(prev stats) + M accumulate, log2 domain ----
            f32x2 M2[8], I2[8];
            #pragma unroll
            for (int q = 0; q < 8; ++q) {
                f32x2 m; m.x = meanS[o*17 + 2*q]; m.y = meanS[o*17 + 2*q + 1];
                f32x2 iv; iv.x = i2vS[o*17 + 2*q] * LOG2E;
                iv.y = i2vS[o*17 + 2*q + 1] * LOG2E;
                M2[q] = m; I2[q] = iv;
            }
            const float base = baseS[o];
            const float bm = (base - redmax32(base)) * LOG2E;  // log2 domain
            #pragma unroll 1
            for (int kk = 0; kk < 18; kk += 2) {
                const int k = k0 + kk;
                E_BODY(k, Pa, Wa, k + 1, Pb, Wb)
                const int kn2 = (kk == 16) ? k0 : k + 2;
                E_BODY(k + 1, Pb, Wb, kn2, Pa, Wa)
            }
        }

        // ---- combine kc pairs (partner lane^32, same wave) -> 8 groups ----
        // VALU-only via permlane32_swap (r0+r1 == x + x[lane^32]).
        S0 = xsum32(S0);
        #pragma unroll
        for (int q = 0; q < 8; ++q) {
            Svp[q].x  = xsum32(Svp[q].x);   Svp[q].y  = xsum32(Svp[q].y);
            Sv2p[q].x = xsum32(Sv2p[q].x);  Sv2p[q].y = xsum32(Sv2p[q].y);
        }
        if ((kc & 1) == 0) {
            float* row = &scr[((kc >> 1)*32 + o)*33];
            #pragma unroll
            for (int q = 0; q < 8; ++q) {
                row[2*q]      = Svp[q].x;  row[2*q + 1]      = Svp[q].y;
                row[16 + 2*q] = Sv2p[q].x; row[16 + 2*q + 1] = Sv2p[q].y;
            }
            row[32] = S0;
        }
        __syncthreads();

        // ---- fused stats + act: thread t handles (oo, pp); each oo group is
        // one 16-lane DPP row, so sum_p(log std) is a 4-step DPP butterfly ----
        {
            float sm = 0.f, s2 = 0.f, rs = 0.f;
            #pragma unroll
            for (int q = 0; q < 8; ++q) {
                const int b0 = (q*32 + oo)*33;
                sm += scr[b0 + pp];
                s2 += scr[b0 + 16 + pp];
                rs += scr[b0 + 32];
            }
            const float inv = 1.0f / (rs + EPSF);
            const float S1  = rs * inv;
            const float m   = sm * inv;
            float var = s2 * inv - m*m*(2.0f - S1);
            var = fmaxf(var, 0.0f) + EPSF;          // std^2 (+eps inside sqrt)
            meanS[oo*17 + pp] = m;
            i2vS [oo*17 + pp] = 0.5f / var;
            const float logstd = 0.5f * __logf(var);
            const float lsum = redsum16(logstd);    // sum over the 16 p's
            const float cost = (16.0f * bu[oo] + lsum) * rs;
            const float ao   = 1.0f / (1.0f + __expf(-lam * (ba[oo] - cost)));
            if (pp == 0) {
                actS[oo]  = ao;
                baseS[oo] = -lsum - 8.0f*LN2PI + __logf(ao);
            }
        }
        __syncthreads();
    }

#undef LOAD_P
#undef VOTES
#undef M0_BODY
#undef E_BODY

    // ---- output: [mean(512) | act(32)] per n ----
    for (int idx = t; idx < 544; idx += 512) {
        const float v = (idx < 512) ? meanS[(idx >> 4)*17 + (idx & 15)]
                                    : actS[idx - 512];
        out[n*544 + idx] = v;
    }
}

} // namespace

extern "C" void kernel_launch(void* const* d_in, const int* in_sizes, int n_in,
                              void* d_out, int out_size, void* d_ws, size_t ws_size,
                              hipStream_t stream) {
    (void)in_sizes; (void)n_in; (void)out_size;
    const float* x  = (const float*)d_in[0];
    const float* W  = (const float*)d_in[1];
    const float* bu = (const float*)d_in[2];
    const float* ba = (const float*)d_in[3];
    float* out = (float*)d_out;

    const size_t need = (size_t)NKK * 32 * 16 * sizeof(float);
    if (d_ws != nullptr && ws_size >= need) {
        float* Wt = (float*)d_ws;
        transpose_w<<<dim3(144), dim3(256), 0, stream>>>(W, Wt);
        caps_em_kernel<true><<<dim3(392), dim3(512), 0, stream>>>(
            x, W, (const float4*)Wt, bu, ba, out);
    } else {
        caps_em_kernel<false><<<dim3(392), dim3(512), 0, stream>>>(
            x, W, nullptr, bu, ba, out);
    }
}